// Round 12
// baseline (1266.288 us; speedup 1.0000x reference)
//
#include <hip/hip_runtime.h>
#include <stdint.h>

// ---------------------------------------------------------------------------
// PairwiseAttentionLinear — fp32 in/out on device.
// Round 12: (1) gemm3b = 128x128 tile, 8 waves of 64x32 (acc=32 VGPR),
// BK=64, 32KB single-buffer LDS, __launch_bounds__(512,6) -> target 3
// blocks/CU (r11 proved occupancy is the lever: 1->2 blocks = +15%).
// (2) bf16 residual stream X (saves ~350MB HBM in aux kernels).
// ---------------------------------------------------------------------------

typedef __bf16 bf16x8 __attribute__((ext_vector_type(8)));
typedef float f32x4 __attribute__((ext_vector_type(4)));

static __device__ __forceinline__ float bf2f(unsigned short u) {
  unsigned int x = ((unsigned int)u) << 16;
  float f;
  __builtin_memcpy(&f, &x, 4);
  return f;
}
static __device__ __forceinline__ unsigned short f2bf(float f) {
  unsigned int x;
  __builtin_memcpy(&x, &f, 4);
  x += 0x7fffu + ((x >> 16) & 1u);  // RNE
  return (unsigned short)(x >> 16);
}

static __device__ __forceinline__ void gload_lds16(const void* g, void* l) {
  __builtin_amdgcn_global_load_lds(
      (const __attribute__((address_space(1))) unsigned int*)g,
      (__attribute__((address_space(3))) unsigned int*)l, 16, 0, 0);
}

__global__ __launch_bounds__(256) void cvt_kernel(
    const float* __restrict__ in, unsigned short* __restrict__ out, long n) {
  const long i = ((long)blockIdx.x * 256 + threadIdx.x) * 4;
  if (i + 3 < n) {
    float4 f = *(const float4*)(in + i);
    *(ushort4*)(out + i) = make_ushort4(f2bf(f.x), f2bf(f.y), f2bf(f.z), f2bf(f.w));
  }
}

// Multi-segment fp32->bf16 (segment lengths multiples of 1024).
#define MAXSEG 14
struct CvtArgs {
  const float* src[MAXSEG];
  unsigned short* dst[MAXSEG];
  long pfx[MAXSEG + 1];
  int ns;
};
__global__ __launch_bounds__(256) void cvt_multi_kernel(CvtArgs a) {
  const long i = ((long)blockIdx.x * 256 + threadIdx.x) * 4;
  int s = 0;
  while (s + 1 < a.ns && i >= a.pfx[s + 1]) ++s;
  const long off = i - a.pfx[s];
  float4 f = *(const float4*)(a.src[s] + off);
  *(ushort4*)(a.dst[s] + off) =
      make_ushort4(f2bf(f.x), f2bf(f.y), f2bf(f.z), f2bf(f.w));
}

// ---------------------------------------------------------------------------
#define BARRIER __builtin_amdgcn_s_barrier()
#define LGKM(N)                                                     \
  do {                                                              \
    asm volatile("s_waitcnt lgkmcnt(" #N ")" ::: "memory");         \
    __builtin_amdgcn_sched_barrier(0);                              \
  } while (0)
#define VMC(N)                                                      \
  do {                                                              \
    asm volatile("s_waitcnt vmcnt(" #N ")" ::: "memory");           \
    __builtin_amdgcn_sched_barrier(0);                              \
  } while (0)

// gemm3b: C[i,j] = act(sum_k A[i,k]*B[j,k] + bias[j]) [+C prior (resadd)]
// 128x128 tile, BK=64, 512 thr, 8 waves 2Mx4N (64x32 each, acc[4][2]).
// LDS 32KB single buffer: A[128][64] @0 | B[128][64] @16384. T2 swizzle
// byte ^= ((row&7)<<4) via pre-swizzled global src + swizzled ds_read.
// resadd on bf16 output reads/accumulates the prior bf16 C content.
__global__ __launch_bounds__(512, 6) void gemm3b_kernel(
    const unsigned short* __restrict__ A, int lda,
    const unsigned short* __restrict__ B, int K,
    void* __restrict__ Cp, int ldc, const float* __restrict__ bias,
    int relu, int out_f32, int resadd,
    const unsigned short* __restrict__ A2, const unsigned short* __restrict__ B2,
    void* __restrict__ C2p, const float* __restrict__ bias2, int dual) {
  __shared__ __align__(16) char smem[32768];

  const int tid = threadIdx.x;
  const int lane = tid & 63;
  const int w = tid >> 6;
  const int wm = w >> 2;  // 0..1
  const int wn = w & 3;   // 0..3
  const long brow = (long)blockIdx.y * 128;

  const unsigned short* Ap = A;
  const unsigned short* Bp = B;
  const float* bi = bias;
  void* Cq = Cp;
  long bcol;
  const int gx = (int)gridDim.x;
  const int bx = (int)blockIdx.x;
  if (dual && bx >= (gx >> 1)) {
    Ap = A2; Bp = B2; bi = bias2; Cq = C2p;
    bcol = (long)(bx - (gx >> 1)) * 128;
  } else {
    bcol = (long)bx * 128;
  }

  const int NT = K >> 6;  // K-tiles of 64

  // staging addressing (pre-swizzled source, linear LDS dest — rule #21)
  const int lrA = tid >> 3;                                    // row 0..63
  const int scb = ((tid & 7) * 16) ^ (((tid >> 3) & 7) << 4);  // pre-swz
  const unsigned wub = (unsigned)(tid & ~63) * 16;             // wave base
  const long ldab = (long)lda * 2;
  const long ldbb = (long)K * 2;
  const char* gA = (const char*)Ap + (brow + lrA) * ldab + scb;
  const char* gB = (const char*)Bp + (bcol + lrA) * ldbb + scb;
  const long a64 = 64 * ldab;
  const long b64 = 64 * ldbb;

#define STAGE(off)                                        \
  do {                                                    \
    gload_lds16(gA + (off), smem + wub);                  \
    gload_lds16(gA + a64 + (off), smem + 8192 + wub);     \
    gload_lds16(gB + (off), smem + 16384 + wub);          \
    gload_lds16(gB + b64 + (off), smem + 24576 + wub);    \
  } while (0)

  f32x4 acc[4][2];
  const f32x4 fz = {0.f, 0.f, 0.f, 0.f};
#pragma unroll
  for (int m = 0; m < 4; ++m)
#pragma unroll
    for (int n = 0; n < 2; ++n) acc[m][n] = fz;

  const int frow = lane & 15;
  const int fkb = (lane >> 4) * 16;  // k-byte within 128B row
  const int fswz = (lane & 7) << 4;  // T2 read-side swizzle

#define RDA(dst, M, KK)                                                       \
  dst = *(const bf16x8*)(smem + (wm * 64 + (M) * 16 + frow) * 128 +           \
                         (((KK) * 64 + fkb) ^ fswz))
#define RDB(dst, N, KK)                                                       \
  dst = *(const bf16x8*)(smem + 16384 + (wn * 32 + (N) * 16 + frow) * 128 +   \
                         (((KK) * 64 + fkb) ^ fswz))

  // 8 MFMAs, one kk: per-acc reuse distance 8
#define MM8(A4, B2)                                                           \
  do {                                                                        \
    _Pragma("unroll") for (int mm = 0; mm < 4; ++mm)                          \
    _Pragma("unroll") for (int nn = 0; nn < 2; ++nn)                          \
        acc[mm][nn] = __builtin_amdgcn_mfma_f32_16x16x32_bf16(                \
            A4[mm], B2[nn], acc[mm][nn], 0, 0, 0);                            \
  } while (0)

  // prologue: stage tile 0 (single buffer)
  STAGE(0);
  long soff = 128;  // byte col-offset of tile t+1

  for (int t = 0; t < NT; ++t) {
    VMC(0);   // own stage loads landed
    BARRIER;  // ...for all waves -> tile t fully in LDS

    bf16x8 a0[4], b0[2];
    RDA(a0[0], 0, 0); RDA(a0[1], 1, 0); RDA(a0[2], 2, 0); RDA(a0[3], 3, 0);
    RDB(b0[0], 0, 0); RDB(b0[1], 1, 0);
    LGKM(0);
    __builtin_amdgcn_s_setprio(1);
    MM8(a0, b0);
    __builtin_amdgcn_s_setprio(0);
    __builtin_amdgcn_sched_barrier(0);

    bf16x8 a1[4], b1[2];
    RDA(a1[0], 0, 1); RDA(a1[1], 1, 1); RDA(a1[2], 2, 1); RDA(a1[3], 3, 1);
    RDB(b1[0], 0, 1); RDB(b1[1], 1, 1);
    LGKM(0);
    BARRIER;  // all waves done reading tile t -> overwrite safe
    if (t + 1 < NT) STAGE(soff);
    __builtin_amdgcn_s_setprio(1);
    MM8(a1, b1);
    __builtin_amdgcn_s_setprio(0);
    __builtin_amdgcn_sched_barrier(0);
    soff += 128;
  }

  // epilogue: C/D layout col=lane&15, row=(lane>>4)*4+reg [m89]
  const long rb0 = brow + wm * 64 + (lane >> 4) * 4;
  const long cb0 = bcol + wn * 32 + (lane & 15);
#pragma unroll
  for (int m = 0; m < 4; ++m) {
#pragma unroll
    for (int n = 0; n < 2; ++n) {
      const long col = cb0 + n * 16;
      const float bv = bi ? bi[col] : 0.f;
#pragma unroll
      for (int j = 0; j < 4; ++j) {
        const long r = rb0 + m * 16 + j;
        float v = acc[m][n][j] + bv;
        if (relu) v = fmaxf(v, 0.f);
        if (out_f32) {
          float* cp = (float*)Cq + r * (long)ldc + col;
          if (resadd) v += *cp;
          *cp = v;
        } else {
          unsigned short* cp = (unsigned short*)Cq + r * (long)ldc + col;
          if (resadd) v += bf2f(*cp);
          *cp = f2bf(v);
        }
      }
    }
  }
#undef STAGE
#undef RDA
#undef RDB
#undef MM8
}

// ---------------------------------------------------------------------------
// Legacy 128x128 GEMM — fallback path only.
// ---------------------------------------------------------------------------
__global__ __launch_bounds__(256) void gemm_bt_kernel(
    const unsigned short* __restrict__ A, int lda,
    const unsigned short* __restrict__ B, int K,
    void* __restrict__ Cp, int ldc,
    const float* __restrict__ bias,
    const void* __restrict__ res, int res_mode, int ldres,
    int relu, int out_f32) {
  __shared__ __align__(16) unsigned short As[128 * 32];
  __shared__ __align__(16) unsigned short Bs[128 * 32];

  const int t = threadIdx.x;
  const int lane = t & 63;
  const int w = t >> 6;
  const int wr = (w >> 1) * 64;
  const int wc = (w & 1) * 64;
  const long brow = (long)blockIdx.y * 128;
  const long bcol = (long)blockIdx.x * 128;

  const int srow = lane >> 2;
  const int scol = (lane & 3) * 8;
  const unsigned short* Ab = A + (brow + w * 32 + srow) * (long)lda + scol;
  const unsigned short* Bb = B + (bcol + w * 32 + srow) * (long)K + scol;
  unsigned short* Asb = &As[(w * 32) * 32];
  unsigned short* Bsb = &Bs[(w * 32) * 32];

  f32x4 acc[4][4];
  const f32x4 fzero = {0.f, 0.f, 0.f, 0.f};
#pragma unroll
  for (int m = 0; m < 4; ++m)
#pragma unroll
    for (int n = 0; n < 4; ++n) acc[m][n] = fzero;

  const int fr = lane & 15;
  const int fk = (lane >> 4) * 8;

  for (int kt = 0; kt < K; kt += 32) {
    gload_lds16(Ab + kt, Asb);
    gload_lds16(Ab + 16 * (long)lda + kt, Asb + 16 * 32);
    gload_lds16(Bb + kt, Bsb);
    gload_lds16(Bb + 16 * (long)K + kt, Bsb + 16 * 32);
    __syncthreads();

    bf16x8 af[4], bfv[4];
#pragma unroll
    for (int m = 0; m < 4; ++m)
      af[m] = *(const bf16x8*)&As[(wr + m * 16 + fr) * 32 + fk];
#pragma unroll
    for (int n = 0; n < 4; ++n)
      bfv[n] = *(const bf16x8*)&Bs[(wc + n * 16 + fr) * 32 + fk];
#pragma unroll
    for (int m = 0; m < 4; ++m)
#pragma unroll
      for (int n = 0; n < 4; ++n)
        acc[m][n] = __builtin_amdgcn_mfma_f32_16x16x32_bf16(af[m], bfv[n],
                                                            acc[m][n], 0, 0, 0);
    __syncthreads();
  }

  const long rbase = brow + wr + (lane >> 4) * 4;
#pragma unroll
  for (int m = 0; m < 4; ++m) {
#pragma unroll
    for (int n = 0; n < 4; ++n) {
      const long col = bcol + wc + n * 16 + fr;
      const float bv = bias ? bias[col] : 0.f;
#pragma unroll
      for (int j = 0; j < 4; ++j) {
        const long r = rbase + m * 16 + j;
        float v = acc[m][n][j] + bv;
        if (relu) v = fmaxf(v, 0.f);
        if (res_mode == 1)
          v += ((const float*)res)[r * (long)ldres + col];
        else if (res_mode == 2)
          v += bf2f(((const unsigned short*)res)[r * (long)ldres + col]);
        if (out_f32)
          ((float*)Cp)[r * (long)ldc + col] = v;
        else
          ((unsigned short*)Cp)[r * (long)ldc + col] = f2bf(v);
      }
    }
  }
}

// ---------------------------------------------------------------------------
template <int L>
__global__ __launch_bounds__(256) void ln_kernel(
    const void* __restrict__ inp, int in_bf16, int ldin,
    const float* __restrict__ g, const float* __restrict__ b,
    unsigned short* __restrict__ outp, int ldout) {
  constexpr int VEC = L / 256;
  const long row = blockIdx.x;
  const int t = threadIdx.x;
  float v[VEC];
  if (in_bf16) {
    const unsigned short* p = (const unsigned short*)inp + row * (long)ldin + t * VEC;
#pragma unroll
    for (int i = 0; i < VEC; i += 4) {
      ushort4 u = *(const ushort4*)(p + i);
      v[i] = bf2f(u.x); v[i + 1] = bf2f(u.y); v[i + 2] = bf2f(u.z); v[i + 3] = bf2f(u.w);
    }
  } else {
    const float* p = (const float*)inp + row * (long)ldin + t * VEC;
#pragma unroll
    for (int i = 0; i < VEC; i += 4) {
      float4 f = *(const float4*)(p + i);
      v[i] = f.x; v[i + 1] = f.y; v[i + 2] = f.z; v[i + 3] = f.w;
    }
  }
  float s = 0.f, sq = 0.f;
#pragma unroll
  for (int i = 0; i < VEC; ++i) { s += v[i]; sq += v[i] * v[i]; }
#pragma unroll
  for (int off = 32; off; off >>= 1) {
    s += __shfl_xor(s, off, 64);
    sq += __shfl_xor(sq, off, 64);
  }
  __shared__ float red[8];
  if ((t & 63) == 0) { red[t >> 6] = s; red[4 + (t >> 6)] = sq; }
  __syncthreads();
  s = red[0] + red[1] + red[2] + red[3];
  sq = red[4] + red[5] + red[6] + red[7];
  const float mean = s * (1.f / L);
  const float var = sq * (1.f / L) - mean * mean;
  const float rstd = rsqrtf(var + 1e-6f);
  unsigned short* op = outp + row * (long)ldout + t * VEC;
  const float* gp = g + t * VEC;
  const float* bp = b + t * VEC;
#pragma unroll
  for (int i = 0; i < VEC; i += 4) {
    float4 gg = *(const float4*)(gp + i);
    float4 bb = *(const float4*)(bp + i);
    *(ushort4*)(op + i) = make_ushort4(
        f2bf((v[i + 0] - mean) * rstd * gg.x + bb.x),
        f2bf((v[i + 1] - mean) * rstd * gg.y + bb.y),
        f2bf((v[i + 2] - mean) * rstd * gg.z + bb.z),
        f2bf((v[i + 3] - mean) * rstd * gg.w + bb.w));
  }
}

// ---------------------------------------------------------------------------
// Pairwise attention glue + optional fused d/t LayerNorms. Xout nullable.
// ---------------------------------------------------------------------------
__global__ __launch_bounds__(512) void attn_glue_kernel(
    const unsigned short* __restrict__ Q, const unsigned short* __restrict__ Kq,
    const unsigned short* __restrict__ V, int ld, const void* __restrict__ Xres,
    int res_bf16, void* __restrict__ Xout, int out_bf16,
    unsigned short* __restrict__ Xout_bf,
    unsigned short* __restrict__ DNp, unsigned short* __restrict__ TNp,
    const float* __restrict__ lnd_g, const float* __restrict__ lnd_b,
    const float* __restrict__ lnt_g, const float* __restrict__ lnt_b) {
  const long row = blockIdx.x;
  const int h = threadIdx.x >> 6;
  const int lane = threadIdx.x & 63;
  const long qbase = row * (long)ld + h * 256;
  const long xbase = row * 2048 + h * 256;
  const int d = lane * 2;

  ushort2 q0 = *(const ushort2*)&Q[qbase + d];
  ushort2 q1 = *(const ushort2*)&Q[qbase + 128 + d];
  ushort2 k0 = *(const ushort2*)&Kq[qbase + d];
  ushort2 k1 = *(const ushort2*)&Kq[qbase + 128 + d];
  ushort2 v0 = *(const ushort2*)&V[qbase + d];
  ushort2 v1 = *(const ushort2*)&V[qbase + 128 + d];

  const float q0x = bf2f(q0.x), q0y = bf2f(q0.y);
  const float q1x = bf2f(q1.x), q1y = bf2f(q1.y);
  const float k0x = bf2f(k0.x), k0y = bf2f(k0.y);
  const float k1x = bf2f(k1.x), k1y = bf2f(k1.y);

  float s00 = q0x * k0x + q0y * k0y;
  float s01 = q0x * k1x + q0y * k1y;
  float s10 = q1x * k0x + q1y * k0y;
  float s11 = q1x * k1x + q1y * k1y;
#pragma unroll
  for (int off = 32; off; off >>= 1) {
    s00 += __shfl_xor(s00, off, 64);
    s01 += __shfl_xor(s01, off, 64);
    s10 += __shfl_xor(s10, off, 64);
    s11 += __shfl_xor(s11, off, 64);
  }
  const float SC = 0.088388347648318447f;  // 1/sqrt(128)
  s00 *= SC; s01 *= SC; s10 *= SC; s11 *= SC;
  const float m0 = fmaxf(s00, s01), m1 = fmaxf(s10, s11);
  const float e00 = __expf(s00 - m0), e01 = __expf(s01 - m0);
  const float e10 = __expf(s10 - m1), e11 = __expf(s11 - m1);
  const float i0 = 1.f / (e00 + e01), i1 = 1.f / (e10 + e11);
  const float a00 = e00 * i0, a01 = e01 * i0;
  const float a10 = e10 * i1, a11 = e11 * i1;

  const float v0x = bf2f(v0.x), v0y = bf2f(v0.y);
  const float v1x = bf2f(v1.x), v1y = bf2f(v1.y);
  float o0x = a00 * v0x + a01 * v1x, o0y = a00 * v0y + a01 * v1y;
  float o1x = a10 * v0x + a11 * v1x, o1y = a10 * v0y + a11 * v1y;

  if (res_bf16) {
    const unsigned short* xr = (const unsigned short*)Xres + xbase;
    ushort2 ra = *(const ushort2*)&xr[d];
    ushort2 rb = *(const ushort2*)&xr[128 + d];
    o0x += bf2f(ra.x); o0y += bf2f(ra.y); o1x += bf2f(rb.x); o1y += bf2f(rb.y);
  } else {
    const float* xr = (const float*)Xres + xbase;
    float2 ra = *(const float2*)&xr[d];
    float2 rb = *(const float2*)&xr[128 + d];
    o0x += ra.x; o0y += ra.y; o1x += rb.x; o1y += rb.y;
  }
  if (Xout) {
    if (out_bf16) {
      unsigned short* xo = (unsigned short*)Xout + xbase;
      *(ushort2*)&xo[d] = make_ushort2(f2bf(o0x), f2bf(o0y));
      *(ushort2*)&xo[128 + d] = make_ushort2(f2bf(o1x), f2bf(o1y));
    } else {
      float* xo = (float*)Xout + xbase;
      *(float2*)&xo[d] = make_float2(o0x, o0y);
      *(float2*)&xo[128 + d] = make_float2(o1x, o1y);
    }
  }
  if (Xout_bf) {
    unsigned short* xb = Xout_bf + xbase;
    *(ushort2*)&xb[d] = make_ushort2(f2bf(o0x), f2bf(o0y));
    *(ushort2*)&xb[128 + d] = make_ushort2(f2bf(o1x), f2bf(o1y));
  }

  if (DNp) {
    float s4 = o0x + o0y + o1x + o1y;
    float q4 = o0x * o0x + o0y * o0y + o1x * o1x + o1y * o1y;
#pragma unroll
    for (int off = 32; off; off >>= 1) {
      s4 += __shfl_xor(s4, off, 64);
      q4 += __shfl_xor(q4, off, 64);
    }
    __shared__ float redS[8], redQ[8];
    if (lane == 0) { redS[h] = s4; redQ[h] = q4; }
    __syncthreads();
    const int b4 = (h >> 2) * 4;
    const float S = redS[b4] + redS[b4 + 1] + redS[b4 + 2] + redS[b4 + 3];
    const float Qs = redQ[b4] + redQ[b4 + 1] + redQ[b4 + 2] + redQ[b4 + 3];
    const float mean = S * (1.f / 1024.f);
    const float var = Qs * (1.f / 1024.f) - mean * mean;
    const float rstd = rsqrtf(var + 1e-6f);
    const float* gp = (h < 4) ? lnd_g : lnt_g;
    const float* bp = (h < 4) ? lnd_b : lnt_b;
    unsigned short* dst = ((h < 4) ? DNp : TNp) + row * 1024;
    const int hc = (h & 3) * 256 + d;
    float2 g0 = *(const float2*)&gp[hc];
    float2 b0 = *(const float2*)&bp[hc];
    *(ushort2*)&dst[hc] = make_ushort2(f2bf((o0x - mean) * rstd * g0.x + b0.x),
                                       f2bf((o0y - mean) * rstd * g0.y + b0.y));
    float2 g1 = *(const float2*)&gp[hc + 128];
    float2 b1 = *(const float2*)&bp[hc + 128];
    *(ushort2*)&dst[hc + 128] =
        make_ushort2(f2bf((o1x - mean) * rstd * g1.x + b1.x),
                     f2bf((o1y - mean) * rstd * g1.y + b1.y));
  }
}

__global__ __launch_bounds__(256) void final_matvec_kernel(
    const unsigned short* __restrict__ Hm, const float* __restrict__ wv,
    const float* __restrict__ b2, float* __restrict__ outp) {
  const long row = blockIdx.x;
  const int t = threadIdx.x;
  ushort4 hv = *(const ushort4*)&Hm[row * 1024 + t * 4];
  float4 wq = *(const float4*)&wv[t * 4];
  float s = bf2f(hv.x) * wq.x + bf2f(hv.y) * wq.y +
            bf2f(hv.z) * wq.z + bf2f(hv.w) * wq.w;
#pragma unroll
  for (int off = 32; off; off >>= 1) s += __shfl_xor(s, off, 64);
  __shared__ float red[4];
  if ((t & 63) == 0) red[t >> 6] = s;
  __syncthreads();
  if (t == 0) outp[row] = red[0] + red[1] + red[2] + red[3] + b2[0];
}

// ---------------------------------------------------------------------------
extern "C" void kernel_launch(void* const* d_in, const int* in_sizes, int n_in,
                              void* d_out, int out_size, void* d_ws,
                              size_t ws_size, hipStream_t stream) {
  const float* x_in = (const float*)d_in[0];
  const float* aln_g = (const float*)d_in[1];
  const float* aln_b = (const float*)d_in[2];
  const float* Wq_f = (const float*)d_in[3];
  const float* Wk_f = (const float*)d_in[4];
  const float* Wv_f = (const float*)d_in[5];
  const float* lnd_g = (const float*)d_in[6];
  const float* lnd_b = (const float*)d_in[7];
  const float* lnt_g = (const float*)d_in[8];
  const float* lnt_b = (const float*)d_in[9];
  const float* Wd1_f = (const float*)d_in[10];
  const float* bd1 = (const float*)d_in[11];
  const float* Wd2_f = (const float*)d_in[12];
  const float* bd2 = (const float*)d_in[13];
  const float* Wt1_f = (const float*)d_in[14];
  const float* bt1 = (const float*)d_in[15];
  const float* Wt2_f = (const float*)d_in[16];
  const float* bt2 = (const float*)d_in[17];
  const float* Wo1_f = (const float*)d_in[18];
  const float* bo1 = (const float*)d_in[19];
  const float* Wo2_f = (const float*)d_in[20];
  const float* bo2 = (const float*)d_in[21];

  const size_t R = 8192, D = 2048, HD = 1024;
  const size_t DD = D * D;
  const size_t WALL = (3 * 3 * DD + 4 * 2 * D * HD + HD * D) * 2;  // 108 MiB
  const size_t SLOT = 3 * DD * 2;                                  // 24 MiB
  const size_t ACT = R * D * 4 + R * D * 2 + R * 6144 * 2;         // 192 MiB

  auto cvt = [&](const float* src, unsigned short* dst, long n) {
    cvt_kernel<<<dim3((unsigned)(n / 1024)), dim3(256), 0, stream>>>(src, dst, n);
  };

  if (ws_size >= ACT + SLOT) {
    // ===================== fast path =====================
    const bool planAll = ws_size >= ACT + WALL;

    char* p = (char*)d_ws;
    unsigned short* Xb = (unsigned short*)p; p += R * D * 4;  // bf16 X (slot kept 64MB)
    unsigned short* XN = (unsigned short*)p; p += R * D * 2;
    unsigned short* QKVb = (unsigned short*)p; p += R * 6144 * 2;
    unsigned short* Warea = (unsigned short*)p;

    unsigned short* H1d = QKVb;
    unsigned short* H1t = QKVb + R * 2048;
    unsigned short* Hfin = QKVb + R * 4096;
    unsigned short* DN = XN;
    unsigned short* TN = XN + R * HD;

    unsigned short* Wqkv_b = Warea;
    unsigned short* Wd1_b = Wqkv_b + 9 * DD;
    unsigned short* Wt1_b = Wd1_b + 2 * D * HD;
    unsigned short* Wd2_b = Wt1_b + 2 * D * HD;
    unsigned short* Wt2_b = Wd2_b + 2 * D * HD;
    unsigned short* Wo1_b = Wt2_b + 2 * D * HD;
    if (planAll) {
      CvtArgs ca;
      int s = 0;
      long pfx = 0;
      auto add = [&](const float* src, unsigned short* dst, long n) {
        ca.src[s] = src; ca.dst[s] = dst; ca.pfx[s] = pfx; pfx += n; ++s;
      };
      for (int n = 0; n < 3; ++n) {
        add(Wq_f + n * DD, Wqkv_b + n * 3 * DD + 0 * DD, (long)DD);
        add(Wk_f + n * DD, Wqkv_b + n * 3 * DD + 1 * DD, (long)DD);
        add(Wv_f + n * DD, Wqkv_b + n * 3 * DD + 2 * DD, (long)DD);
      }
      add(Wd1_f, Wd1_b, (long)(2 * D * HD));
      add(Wt1_f, Wt1_b, (long)(2 * D * HD));
      add(Wd2_f, Wd2_b, (long)(2 * D * HD));
      add(Wt2_f, Wt2_b, (long)(2 * D * HD));
      add(Wo1_f, Wo1_b, (long)(HD * D));
      ca.pfx[s] = pfx;
      ca.ns = s;
      cvt_multi_kernel<<<dim3((unsigned)(pfx / 1024)), dim3(256), 0, stream>>>(ca);
    }

    auto gemm = [&](const unsigned short* A, int lda, const unsigned short* B,
                    int N, int K, void* C, int ldc, const float* bias,
                    int relu, int of32, int resadd, const unsigned short* A2,
                    const unsigned short* B2, void* C2, const float* bias2) {
      const int dual = (A2 != nullptr);
      dim3 grid((dual ? 2 : 1) * (N / 128), 64);
      gemm3b_kernel<<<grid, dim3(512), 0, stream>>>(
          A, lda, B, K, C, ldc, bias, relu, of32, resadd, A2, B2, C2, bias2,
          dual);
    };

    for (int n = 0; n < 3; ++n) {
      // LN over residual stream: n=0 reads fp32 x_in, else bf16 Xb
      ln_kernel<2048><<<8192, 256, 0, stream>>>(
          (n == 0) ? (const void*)x_in : (const void*)Xb, n != 0, 2048,
          aln_g + n * D, aln_b + n * D, XN, 2048);
      const unsigned short* Wqkv;
      if (planAll) {
        Wqkv = Wqkv_b + (size_t)n * 3 * DD;
      } else {
        cvt(Wq_f + n * DD, Warea + 0 * DD, DD);
        cvt(Wk_f + n * DD, Warea + 1 * DD, DD);
        cvt(Wv_f + n * DD, Warea + 2 * DD, DD);
        Wqkv = Warea;
      }
      gemm(XN, 2048, Wqkv, 6144, 2048, QKVb, 6144, nullptr, 0, 0, 0,
           nullptr, nullptr, nullptr, nullptr);
      // X stream bf16: residual in (fp32 x_in at n=0, else Xb), out bf16 Xb
      attn_glue_kernel<<<8192, 512, 0, stream>>>(
          QKVb, QKVb + 2048, QKVb + 4096, 6144,
          (n == 0) ? (const void*)x_in : (const void*)Xb, n != 0,
          (void*)Xb, 1, nullptr,
          (n < 2) ? DN : nullptr, (n < 2) ? TN : nullptr,
          (n < 2) ? lnd_g + n * HD : nullptr, (n < 2) ? lnd_b + n * HD : nullptr,
          (n < 2) ? lnt_g + n * HD : nullptr, (n < 2) ? lnt_b + n * HD : nullptr);

      if (n < 2) {
        const size_t fo = (size_t)n * D * HD;
        const unsigned short *w1d, *w1t, *w2d, *w2t;
        if (planAll) {
          w1d = Wd1_b + fo; w1t = Wt1_b + fo; w2d = Wd2_b + fo; w2t = Wt2_b + fo;
        } else {
          cvt(Wd1_f + fo, Warea + 0 * D * HD, D * HD);
          cvt(Wt1_f + fo, Warea + 1 * D * HD, D * HD);
          cvt(Wd2_f + fo, Warea + 2 * D * HD, D * HD);
          cvt(Wt2_f + fo, Warea + 3 * D * HD, D * HD);
          w1d = Warea; w1t = Warea + D * HD; w2d = Warea + 2 * D * HD;
          w2t = Warea + 3 * D * HD;
        }
        // dual up-proj: DN -> H1d, TN -> H1t (bf16 out, relu)
        gemm(DN, 1024, w1d, 2048, 1024, H1d, 2048, bd1 + n * D, 1, 0, 0,
             TN, w1t, H1t, bt1 + n * D);
        // dual down-proj with bf16 resadd into Xb halves
        gemm(H1d, 2048, w2d, 1024, 2048, Xb, 2048, bd2 + n * HD, 0, 0, 1,
             H1t, w2t, Xb + HD, bt2 + n * HD);
      }
    }

    // final head: Hfin = relu(Xb @ Wo1^T + bo1); out = Hfin @ Wo2^T + bo2
    const unsigned short* Wo1p;
    if (planAll) {
      Wo1p = Wo1_b;
    } else {
      cvt(Wo1_f, Warea, HD * D);
      Wo1p = Warea;
    }
    gemm(Xb, 2048, Wo1p, 1024, 2048, Hfin, 1024, bo1, 1, 0, 0,
         nullptr, nullptr, nullptr, nullptr);
    final_matvec_kernel<<<8192, 256, 0, stream>>>(Hfin, Wo2_f, bo2,
                                                  (float*)d_out);
    return;
  }

  // ======================= legacy fallback path =======================
  const size_t PLB = R * D * 2;
  const size_t XFZ = R * D * 4;
  const size_t SLOT1 = DD * 2;
  const bool planAll = ws_size >= XFZ + 4 * PLB + WALL;
  const bool xIsF32 = planAll || ws_size >= XFZ + 4 * PLB + SLOT1;

  char* p = (char*)d_ws;
  float* Xf = nullptr;
  unsigned short* Xbb = nullptr;
  if (xIsF32) { Xf = (float*)p; p += XFZ; } else { Xbb = (unsigned short*)p; p += PLB; }
  unsigned short* XN = (unsigned short*)p; p += PLB;
  unsigned short* Qb = (unsigned short*)p; p += PLB;
  unsigned short* Kb = (unsigned short*)p; p += PLB;
  unsigned short* Vb = (unsigned short*)p; p += PLB;
  unsigned short* Warea = (unsigned short*)p;

  void* X = xIsF32 ? (void*)Xf : (void*)Xbb;
  const int xres_mode = xIsF32 ? 1 : 2;
  unsigned short* H1 = Qb;
  unsigned short* DN = XN;
  unsigned short* TN = XN + R * HD;
  unsigned short* Hfin = Vb;

  unsigned short* Wq_b = Warea;
  unsigned short* Wk_b = Wq_b + 3 * DD;
  unsigned short* Wv_b = Wk_b + 3 * DD;
  unsigned short* Wd1_b = Wv_b + 3 * DD;
  unsigned short* Wd2_b = Wd1_b + 2 * D * HD;
  unsigned short* Wt1_b = Wd2_b + 2 * D * HD;
  unsigned short* Wt2_b = Wt1_b + 2 * D * HD;
  unsigned short* Wo1_b = Wt2_b + 2 * D * HD;
  if (planAll) {
    cvt(Wq_f, Wq_b, 3 * DD);
    cvt(Wk_f, Wk_b, 3 * DD);
    cvt(Wv_f, Wv_b, 3 * DD);
    cvt(Wd1_f, Wd1_b, 2 * D * HD);
    cvt(Wd2_f, Wd2_b, 2 * D * HD);
    cvt(Wt1_f, Wt1_b, 2 * D * HD);
    cvt(Wt2_f, Wt2_b, 2 * D * HD);
    cvt(Wo1_f, Wo1_b, HD * D);
  }
  auto wbf = [&](const float* src_base, unsigned short* pre_base, size_t off,
                 size_t cnt) -> const unsigned short* {
    if (planAll) return pre_base + off;
    cvt(src_base + off, Warea, (long)cnt);
    return Warea;
  };
  auto gemm = [&](const unsigned short* A, int lda, const unsigned short* B,
                  int N, int K, void* C, int ldc, const float* bias,
                  const void* res, int res_mode, int ldres, int relu, int of32) {
    dim3 grid(N / 128, 8192 / 128);
    gemm_bt_kernel<<<grid, dim3(256), 0, stream>>>(
        A, lda, B, K, C, ldc, bias, res, res_mode, ldres, relu, of32);
  };

  for (int n = 0; n < 3; ++n) {
    const void* lin = (n == 0) ? (const void*)x_in : (const void*)X;
    const int lin_bf16 = (n == 0) ? 0 : (xIsF32 ? 0 : 1);
    ln_kernel<2048><<<8192, 256, 0, stream>>>(lin, lin_bf16, 2048,
                                              aln_g + n * D, aln_b + n * D, XN, 2048);
    const size_t wo = (size_t)n * DD;
    gemm(XN, 2048, wbf(Wq_f, Wq_b, wo, DD), 2048, 2048, Qb, 2048,
         nullptr, nullptr, 0, 0, 0, 0);
    gemm(XN, 2048, wbf(Wk_f, Wk_b, wo, DD), 2048, 2048, Kb, 2048,
         nullptr, nullptr, 0, 0, 0, 0);
    gemm(XN, 2048, wbf(Wv_f, Wv_b, wo, DD), 2048, 2048, Vb, 2048,
         nullptr, nullptr, 0, 0, 0, 0);
    attn_glue_kernel<<<8192, 512, 0, stream>>>(
        Qb, Kb, Vb, 2048, (n == 0) ? (const void*)x_in : (const void*)X,
        (n == 0) ? 0 : (xIsF32 ? 0 : 1), X, xIsF32 ? 0 : 1,
        (n == 2 && xIsF32) ? XN : nullptr,
        nullptr, nullptr, nullptr, nullptr, nullptr, nullptr);

    if (n < 2) {
      const size_t fo = (size_t)n * D * HD;
      ln_kernel<1024><<<8192, 256, 0, stream>>>(X, !xIsF32, 2048,
                                                lnd_g + n * HD, lnd_b + n * HD, DN, 1024);
      const void* Xt = xIsF32 ? (const void*)(Xf + HD) : (const void*)(Xbb + HD);
      ln_kernel<1024><<<8192, 256, 0, stream>>>(Xt, !xIsF32, 2048,
                                                lnt_g + n * HD, lnt_b + n * HD, TN, 1024);
      void* Xd2 = X;
      void* Xt2 = xIsF32 ? (void*)(Xf + HD) : (void*)(Xbb + HD);
      gemm(DN, 1024, wbf(Wd1_f, Wd1_b, fo, D * HD), 2048, 1024, H1, 2048,
           bd1 + n * D, nullptr, 0, 0, 1, 0);
      gemm(H1, 2048, wbf(Wd2_f, Wd2_b, fo, D * HD), 1024, 2048, Xd2, 2048,
           bd2 + n * HD, Xd2, xres_mode, 2048, 0, xIsF32 ? 1 : 0);
      gemm(TN, 1024, wbf(Wt1_f, Wt1_b, fo, D * HD), 2048, 1024, H1, 2048,
           bt1 + n * D, nullptr, 0, 0, 1, 0);
      gemm(H1, 2048, wbf(Wt2_f, Wt2_b, fo, D * HD), 1024, 2048, Xt2, 2048,
           bt2 + n * HD, Xt2, xres_mode, 2048, 0, xIsF32 ? 1 : 0);
    }
  }

  const unsigned short* Afin = xIsF32 ? XN : Xbb;
  gemm(Afin, 2048, wbf(Wo1_f, Wo1_b, 0, HD * D), 1024, 2048, Hfin, 1024,
       bo1, nullptr, 0, 0, 1, 0);
  final_matvec_kernel<<<8192, 256, 0, stream>>>(Hfin, Wo2_f, bo2, (float*)d_out);
}

// Round 13
// 1193.622 us; speedup vs baseline: 1.0609x; 1.0609x over previous
//
#include <hip/hip_runtime.h>
#include <stdint.h>

// ---------------------------------------------------------------------------
// PairwiseAttentionLinear — fp32 in/out on device.
// Round 13: recombination of measured winners: gemm2b (r11: 256x128 tile,
// 2 blocks/CU via 48KB LDS + 64-VGPR acc — QKV 192us) + bf16 residual
// stream X (r12: validated absmax 0.0159, aux traffic halved). gemm2b
// epilogue gains bf16-resadd (pattern validated in r12's gemm3b).
// ---------------------------------------------------------------------------

typedef __bf16 bf16x8 __attribute__((ext_vector_type(8)));
typedef float f32x4 __attribute__((ext_vector_type(4)));

static __device__ __forceinline__ float bf2f(unsigned short u) {
  unsigned int x = ((unsigned int)u) << 16;
  float f;
  __builtin_memcpy(&f, &x, 4);
  return f;
}
static __device__ __forceinline__ unsigned short f2bf(float f) {
  unsigned int x;
  __builtin_memcpy(&x, &f, 4);
  x += 0x7fffu + ((x >> 16) & 1u);  // RNE
  return (unsigned short)(x >> 16);
}

static __device__ __forceinline__ void gload_lds16(const void* g, void* l) {
  __builtin_amdgcn_global_load_lds(
      (const __attribute__((address_space(1))) unsigned int*)g,
      (__attribute__((address_space(3))) unsigned int*)l, 16, 0, 0);
}

__global__ __launch_bounds__(256) void cvt_kernel(
    const float* __restrict__ in, unsigned short* __restrict__ out, long n) {
  const long i = ((long)blockIdx.x * 256 + threadIdx.x) * 4;
  if (i + 3 < n) {
    float4 f = *(const float4*)(in + i);
    *(ushort4*)(out + i) = make_ushort4(f2bf(f.x), f2bf(f.y), f2bf(f.z), f2bf(f.w));
  }
}

// Multi-segment fp32->bf16 (segment lengths multiples of 1024).
#define MAXSEG 14
struct CvtArgs {
  const float* src[MAXSEG];
  unsigned short* dst[MAXSEG];
  long pfx[MAXSEG + 1];
  int ns;
};
__global__ __launch_bounds__(256) void cvt_multi_kernel(CvtArgs a) {
  const long i = ((long)blockIdx.x * 256 + threadIdx.x) * 4;
  int s = 0;
  while (s + 1 < a.ns && i >= a.pfx[s + 1]) ++s;
  const long off = i - a.pfx[s];
  float4 f = *(const float4*)(a.src[s] + off);
  *(ushort4*)(a.dst[s] + off) =
      make_ushort4(f2bf(f.x), f2bf(f.y), f2bf(f.z), f2bf(f.w));
}

// ---------------------------------------------------------------------------
#define BARRIER __builtin_amdgcn_s_barrier()
#define LGKM(N)                                                     \
  do {                                                              \
    asm volatile("s_waitcnt lgkmcnt(" #N ")" ::: "memory");         \
    __builtin_amdgcn_sched_barrier(0);                              \
  } while (0)
#define VMC(N)                                                      \
  do {                                                              \
    asm volatile("s_waitcnt vmcnt(" #N ")" ::: "memory");           \
    __builtin_amdgcn_sched_barrier(0);                              \
  } while (0)

// gemm2b: C[i,j] = act(sum_k A[i,k]*B[j,k] + bias[j]) [+C prior (resadd)]
// 256x128 tile, BK=64, 512 thr, 8 waves 4Mx2N (64x64 each). LDS 48KB single
// buffer: A[256][64] @0 (32KB) | B[128][64] @32768 (16KB). T2 swizzle
// byte ^= ((row&7)<<4) via pre-swizzled global src + swizzled ds_read.
// dual: blocks with bx >= gridDim.x/2 use second operand set.
__global__ __launch_bounds__(512, 4) void gemm2b_kernel(
    const unsigned short* __restrict__ A, int lda,
    const unsigned short* __restrict__ B, int K,
    void* __restrict__ Cp, int ldc, const float* __restrict__ bias,
    int relu, int out_f32, int resadd,
    const unsigned short* __restrict__ A2, const unsigned short* __restrict__ B2,
    void* __restrict__ C2p, const float* __restrict__ bias2, int dual) {
  __shared__ __align__(16) char smem[49152];

  const int tid = threadIdx.x;
  const int lane = tid & 63;
  const int w = tid >> 6;
  const int wm = w >> 1;  // 0..3
  const int wn = w & 1;   // 0..1
  const long brow = (long)blockIdx.y * 256;

  const unsigned short* Ap = A;
  const unsigned short* Bp = B;
  const float* bi = bias;
  void* Cq = Cp;
  long bcol;
  const int gx = (int)gridDim.x;
  const int bx = (int)blockIdx.x;
  if (dual && bx >= (gx >> 1)) {
    Ap = A2; Bp = B2; bi = bias2; Cq = C2p;
    bcol = (long)(bx - (gx >> 1)) * 128;
  } else {
    bcol = (long)bx * 128;
  }

  const int NT = K >> 6;  // K-tiles of 64

  // staging addressing (pre-swizzled source, linear LDS dest — rule #21)
  const int lrA = tid >> 3;                                    // row 0..63
  const int scb = ((tid & 7) * 16) ^ (((tid >> 3) & 7) << 4);  // pre-swz
  const unsigned wb = (unsigned)tid * 16;                      // linear dest
  const long ldab = (long)lda * 2;
  const long ldbb = (long)K * 2;
  const char* gA = (const char*)Ap + (brow + lrA) * ldab + scb;
  const char* gB = (const char*)Bp + (bcol + lrA) * ldbb + scb;
  const long a64 = 64 * ldab, a128 = 128 * ldab, a192 = 192 * ldab;
  const long b64 = 64 * ldbb;

#define STAGE(off)                                              \
  do {                                                          \
    gload_lds16(gA + (off), smem + (wb & ~1023u));              \
    gload_lds16(gA + a64 + (off), smem + 8192 + (wb & ~1023u)); \
    gload_lds16(gA + a128 + (off), smem + 16384 + (wb & ~1023u)); \
    gload_lds16(gA + a192 + (off), smem + 24576 + (wb & ~1023u)); \
    gload_lds16(gB + (off), smem + 32768 + (wb & ~1023u));      \
    gload_lds16(gB + b64 + (off), smem + 40960 + (wb & ~1023u)); \
  } while (0)

  f32x4 acc[4][4];
  const f32x4 fz = {0.f, 0.f, 0.f, 0.f};
#pragma unroll
  for (int m = 0; m < 4; ++m)
#pragma unroll
    for (int n = 0; n < 4; ++n) acc[m][n] = fz;

  const int frow = lane & 15;
  const int fkb = (lane >> 4) * 16;  // k-byte within 128B row
  const int fswz = (lane & 7) << 4;  // T2 read-side swizzle

#define RDA(dst, M, KK)                                                       \
  dst = *(const bf16x8*)(smem + (wm * 64 + (M) * 16 + frow) * 128 +           \
                         (((KK) * 64 + fkb) ^ fswz))
#define RDB(dst, N, KK)                                                       \
  dst = *(const bf16x8*)(smem + 32768 + (wn * 64 + (N) * 16 + frow) * 128 +   \
                         (((KK) * 64 + fkb) ^ fswz))

  // 16 MFMAs, one kk: per-acc reuse distance 16
#define MM16(A4, B4)                                                          \
  do {                                                                        \
    _Pragma("unroll") for (int mm = 0; mm < 4; ++mm)                          \
    _Pragma("unroll") for (int nn = 0; nn < 4; ++nn)                          \
        acc[mm][nn] = __builtin_amdgcn_mfma_f32_16x16x32_bf16(                \
            A4[mm], B4[nn], acc[mm][nn], 0, 0, 0);                            \
  } while (0)

  // prologue: stage tile 0 (single buffer)
  STAGE(0);
  long soff = 128;  // byte col-offset of tile t+1

  for (int t = 0; t < NT; ++t) {
    VMC(0);   // own stage loads landed
    BARRIER;  // ...for all waves -> tile t fully in LDS

    bf16x8 a0[4], b0[4];
    RDA(a0[0], 0, 0); RDA(a0[1], 1, 0); RDA(a0[2], 2, 0); RDA(a0[3], 3, 0);
    RDB(b0[0], 0, 0); RDB(b0[1], 1, 0); RDB(b0[2], 2, 0); RDB(b0[3], 3, 0);
    LGKM(0);
    __builtin_amdgcn_s_setprio(1);
    MM16(a0, b0);
    __builtin_amdgcn_s_setprio(0);
    __builtin_amdgcn_sched_barrier(0);

    bf16x8 a1[4], b1[4];
    RDA(a1[0], 0, 1); RDA(a1[1], 1, 1); RDA(a1[2], 2, 1); RDA(a1[3], 3, 1);
    RDB(b1[0], 0, 1); RDB(b1[1], 1, 1); RDB(b1[2], 2, 1); RDB(b1[3], 3, 1);
    LGKM(0);
    BARRIER;  // all waves done reading tile t -> overwrite safe
    if (t + 1 < NT) STAGE(soff);
    __builtin_amdgcn_s_setprio(1);
    MM16(a1, b1);
    __builtin_amdgcn_s_setprio(0);
    __builtin_amdgcn_sched_barrier(0);
    soff += 128;
  }

  // epilogue: C/D layout col=lane&15, row=(lane>>4)*4+reg [m89]
  const long rb0 = brow + wm * 64 + (lane >> 4) * 4;
  const long cb0 = bcol + wn * 64 + (lane & 15);
#pragma unroll
  for (int m = 0; m < 4; ++m) {
#pragma unroll
    for (int n = 0; n < 4; ++n) {
      const long col = cb0 + n * 16;
      const float bv = bi ? bi[col] : 0.f;
#pragma unroll
      for (int j = 0; j < 4; ++j) {
        const long r = rb0 + m * 16 + j;
        float v = acc[m][n][j] + bv;
        if (relu) v = fmaxf(v, 0.f);
        if (out_f32) {
          float* cp = (float*)Cq + r * (long)ldc + col;
          if (resadd) v += *cp;
          *cp = v;
        } else {
          unsigned short* cp = (unsigned short*)Cq + r * (long)ldc + col;
          if (resadd) v += bf2f(*cp);
          *cp = f2bf(v);
        }
      }
    }
  }
#undef STAGE
#undef RDA
#undef RDB
#undef MM16
}

// ---------------------------------------------------------------------------
// Legacy 128x128 GEMM — fallback path only.
// ---------------------------------------------------------------------------
__global__ __launch_bounds__(256) void gemm_bt_kernel(
    const unsigned short* __restrict__ A, int lda,
    const unsigned short* __restrict__ B, int K,
    void* __restrict__ Cp, int ldc,
    const float* __restrict__ bias,
    const void* __restrict__ res, int res_mode, int ldres,
    int relu, int out_f32) {
  __shared__ __align__(16) unsigned short As[128 * 32];
  __shared__ __align__(16) unsigned short Bs[128 * 32];

  const int t = threadIdx.x;
  const int lane = t & 63;
  const int w = t >> 6;
  const int wr = (w >> 1) * 64;
  const int wc = (w & 1) * 64;
  const long brow = (long)blockIdx.y * 128;
  const long bcol = (long)blockIdx.x * 128;

  const int srow = lane >> 2;
  const int scol = (lane & 3) * 8;
  const unsigned short* Ab = A + (brow + w * 32 + srow) * (long)lda + scol;
  const unsigned short* Bb = B + (bcol + w * 32 + srow) * (long)K + scol;
  unsigned short* Asb = &As[(w * 32) * 32];
  unsigned short* Bsb = &Bs[(w * 32) * 32];

  f32x4 acc[4][4];
  const f32x4 fzero = {0.f, 0.f, 0.f, 0.f};
#pragma unroll
  for (int m = 0; m < 4; ++m)
#pragma unroll
    for (int n = 0; n < 4; ++n) acc[m][n] = fzero;

  const int fr = lane & 15;
  const int fk = (lane >> 4) * 8;

  for (int kt = 0; kt < K; kt += 32) {
    gload_lds16(Ab + kt, Asb);
    gload_lds16(Ab + 16 * (long)lda + kt, Asb + 16 * 32);
    gload_lds16(Bb + kt, Bsb);
    gload_lds16(Bb + 16 * (long)K + kt, Bsb + 16 * 32);
    __syncthreads();

    bf16x8 af[4], bfv[4];
#pragma unroll
    for (int m = 0; m < 4; ++m)
      af[m] = *(const bf16x8*)&As[(wr + m * 16 + fr) * 32 + fk];
#pragma unroll
    for (int n = 0; n < 4; ++n)
      bfv[n] = *(const bf16x8*)&Bs[(wc + n * 16 + fr) * 32 + fk];
#pragma unroll
    for (int m = 0; m < 4; ++m)
#pragma unroll
      for (int n = 0; n < 4; ++n)
        acc[m][n] = __builtin_amdgcn_mfma_f32_16x16x32_bf16(af[m], bfv[n],
                                                            acc[m][n], 0, 0, 0);
    __syncthreads();
  }

  const long rbase = brow + wr + (lane >> 4) * 4;
#pragma unroll
  for (int m = 0; m < 4; ++m) {
#pragma unroll
    for (int n = 0; n < 4; ++n) {
      const long col = bcol + wc + n * 16 + fr;
      const float bv = bias ? bias[col] : 0.f;
#pragma unroll
      for (int j = 0; j < 4; ++j) {
        const long r = rbase + m * 16 + j;
        float v = acc[m][n][j] + bv;
        if (relu) v = fmaxf(v, 0.f);
        if (res_mode == 1)
          v += ((const float*)res)[r * (long)ldres + col];
        else if (res_mode == 2)
          v += bf2f(((const unsigned short*)res)[r * (long)ldres + col]);
        if (out_f32)
          ((float*)Cp)[r * (long)ldc + col] = v;
        else
          ((unsigned short*)Cp)[r * (long)ldc + col] = f2bf(v);
      }
    }
  }
}

// ---------------------------------------------------------------------------
template <int L>
__global__ __launch_bounds__(256) void ln_kernel(
    const void* __restrict__ inp, int in_bf16, int ldin,
    const float* __restrict__ g, const float* __restrict__ b,
    unsigned short* __restrict__ outp, int ldout) {
  constexpr int VEC = L / 256;
  const long row = blockIdx.x;
  const int t = threadIdx.x;
  float v[VEC];
  if (in_bf16) {
    const unsigned short* p = (const unsigned short*)inp + row * (long)ldin + t * VEC;
#pragma unroll
    for (int i = 0; i < VEC; i += 4) {
      ushort4 u = *(const ushort4*)(p + i);
      v[i] = bf2f(u.x); v[i + 1] = bf2f(u.y); v[i + 2] = bf2f(u.z); v[i + 3] = bf2f(u.w);
    }
  } else {
    const float* p = (const float*)inp + row * (long)ldin + t * VEC;
#pragma unroll
    for (int i = 0; i < VEC; i += 4) {
      float4 f = *(const float4*)(p + i);
      v[i] = f.x; v[i + 1] = f.y; v[i + 2] = f.z; v[i + 3] = f.w;
    }
  }
  float s = 0.f, sq = 0.f;
#pragma unroll
  for (int i = 0; i < VEC; ++i) { s += v[i]; sq += v[i] * v[i]; }
#pragma unroll
  for (int off = 32; off; off >>= 1) {
    s += __shfl_xor(s, off, 64);
    sq += __shfl_xor(sq, off, 64);
  }
  __shared__ float red[8];
  if ((t & 63) == 0) { red[t >> 6] = s; red[4 + (t >> 6)] = sq; }
  __syncthreads();
  s = red[0] + red[1] + red[2] + red[3];
  sq = red[4] + red[5] + red[6] + red[7];
  const float mean = s * (1.f / L);
  const float var = sq * (1.f / L) - mean * mean;
  const float rstd = rsqrtf(var + 1e-6f);
  unsigned short* op = outp + row * (long)ldout + t * VEC;
  const float* gp = g + t * VEC;
  const float* bp = b + t * VEC;
#pragma unroll
  for (int i = 0; i < VEC; i += 4) {
    float4 gg = *(const float4*)(gp + i);
    float4 bb = *(const float4*)(bp + i);
    *(ushort4*)(op + i) = make_ushort4(
        f2bf((v[i + 0] - mean) * rstd * gg.x + bb.x),
        f2bf((v[i + 1] - mean) * rstd * gg.y + bb.y),
        f2bf((v[i + 2] - mean) * rstd * gg.z + bb.z),
        f2bf((v[i + 3] - mean) * rstd * gg.w + bb.w));
  }
}

// ---------------------------------------------------------------------------
// Pairwise attention glue + optional fused d/t LayerNorms. Xout nullable.
// ---------------------------------------------------------------------------
__global__ __launch_bounds__(512) void attn_glue_kernel(
    const unsigned short* __restrict__ Q, const unsigned short* __restrict__ Kq,
    const unsigned short* __restrict__ V, int ld, const void* __restrict__ Xres,
    int res_bf16, void* __restrict__ Xout, int out_bf16,
    unsigned short* __restrict__ Xout_bf,
    unsigned short* __restrict__ DNp, unsigned short* __restrict__ TNp,
    const float* __restrict__ lnd_g, const float* __restrict__ lnd_b,
    const float* __restrict__ lnt_g, const float* __restrict__ lnt_b) {
  const long row = blockIdx.x;
  const int h = threadIdx.x >> 6;
  const int lane = threadIdx.x & 63;
  const long qbase = row * (long)ld + h * 256;
  const long xbase = row * 2048 + h * 256;
  const int d = lane * 2;

  ushort2 q0 = *(const ushort2*)&Q[qbase + d];
  ushort2 q1 = *(const ushort2*)&Q[qbase + 128 + d];
  ushort2 k0 = *(const ushort2*)&Kq[qbase + d];
  ushort2 k1 = *(const ushort2*)&Kq[qbase + 128 + d];
  ushort2 v0 = *(const ushort2*)&V[qbase + d];
  ushort2 v1 = *(const ushort2*)&V[qbase + 128 + d];

  const float q0x = bf2f(q0.x), q0y = bf2f(q0.y);
  const float q1x = bf2f(q1.x), q1y = bf2f(q1.y);
  const float k0x = bf2f(k0.x), k0y = bf2f(k0.y);
  const float k1x = bf2f(k1.x), k1y = bf2f(k1.y);

  float s00 = q0x * k0x + q0y * k0y;
  float s01 = q0x * k1x + q0y * k1y;
  float s10 = q1x * k0x + q1y * k0y;
  float s11 = q1x * k1x + q1y * k1y;
#pragma unroll
  for (int off = 32; off; off >>= 1) {
    s00 += __shfl_xor(s00, off, 64);
    s01 += __shfl_xor(s01, off, 64);
    s10 += __shfl_xor(s10, off, 64);
    s11 += __shfl_xor(s11, off, 64);
  }
  const float SC = 0.088388347648318447f;  // 1/sqrt(128)
  s00 *= SC; s01 *= SC; s10 *= SC; s11 *= SC;
  const float m0 = fmaxf(s00, s01), m1 = fmaxf(s10, s11);
  const float e00 = __expf(s00 - m0), e01 = __expf(s01 - m0);
  const float e10 = __expf(s10 - m1), e11 = __expf(s11 - m1);
  const float i0 = 1.f / (e00 + e01), i1 = 1.f / (e10 + e11);
  const float a00 = e00 * i0, a01 = e01 * i0;
  const float a10 = e10 * i1, a11 = e11 * i1;

  const float v0x = bf2f(v0.x), v0y = bf2f(v0.y);
  const float v1x = bf2f(v1.x), v1y = bf2f(v1.y);
  float o0x = a00 * v0x + a01 * v1x, o0y = a00 * v0y + a01 * v1y;
  float o1x = a10 * v0x + a11 * v1x, o1y = a10 * v0y + a11 * v1y;

  if (res_bf16) {
    const unsigned short* xr = (const unsigned short*)Xres + xbase;
    ushort2 ra = *(const ushort2*)&xr[d];
    ushort2 rb = *(const ushort2*)&xr[128 + d];
    o0x += bf2f(ra.x); o0y += bf2f(ra.y); o1x += bf2f(rb.x); o1y += bf2f(rb.y);
  } else {
    const float* xr = (const float*)Xres + xbase;
    float2 ra = *(const float2*)&xr[d];
    float2 rb = *(const float2*)&xr[128 + d];
    o0x += ra.x; o0y += ra.y; o1x += rb.x; o1y += rb.y;
  }
  if (Xout) {
    if (out_bf16) {
      unsigned short* xo = (unsigned short*)Xout + xbase;
      *(ushort2*)&xo[d] = make_ushort2(f2bf(o0x), f2bf(o0y));
      *(ushort2*)&xo[128 + d] = make_ushort2(f2bf(o1x), f2bf(o1y));
    } else {
      float* xo = (float*)Xout + xbase;
      *(float2*)&xo[d] = make_float2(o0x, o0y);
      *(float2*)&xo[128 + d] = make_float2(o1x, o1y);
    }
  }
  if (Xout_bf) {
    unsigned short* xb = Xout_bf + xbase;
    *(ushort2*)&xb[d] = make_ushort2(f2bf(o0x), f2bf(o0y));
    *(ushort2*)&xb[128 + d] = make_ushort2(f2bf(o1x), f2bf(o1y));
  }

  if (DNp) {
    float s4 = o0x + o0y + o1x + o1y;
    float q4 = o0x * o0x + o0y * o0y + o1x * o1x + o1y * o1y;
#pragma unroll
    for (int off = 32; off; off >>= 1) {
      s4 += __shfl_xor(s4, off, 64);
      q4 += __shfl_xor(q4, off, 64);
    }
    __shared__ float redS[8], redQ[8];
    if (lane == 0) { redS[h] = s4; redQ[h] = q4; }
    __syncthreads();
    const int b4 = (h >> 2) * 4;
    const float S = redS[b4] + redS[b4 + 1] + redS[b4 + 2] + redS[b4 + 3];
    const float Qs = redQ[b4] + redQ[b4 + 1] + redQ[b4 + 2] + redQ[b4 + 3];
    const float mean = S * (1.f / 1024.f);
    const float var = Qs * (1.f / 1024.f) - mean * mean;
    const float rstd = rsqrtf(var + 1e-6f);
    const float* gp = (h < 4) ? lnd_g : lnt_g;
    const float* bp = (h < 4) ? lnd_b : lnt_b;
    unsigned short* dst = ((h < 4) ? DNp : TNp) + row * 1024;
    const int hc = (h & 3) * 256 + d;
    float2 g0 = *(const float2*)&gp[hc];
    float2 b0 = *(const float2*)&bp[hc];
    *(ushort2*)&dst[hc] = make_ushort2(f2bf((o0x - mean) * rstd * g0.x + b0.x),
                                       f2bf((o0y - mean) * rstd * g0.y + b0.y));
    float2 g1 = *(const float2*)&gp[hc + 128];
    float2 b1 = *(const float2*)&bp[hc + 128];
    *(ushort2*)&dst[hc + 128] =
        make_ushort2(f2bf((o1x - mean) * rstd * g1.x + b1.x),
                     f2bf((o1y - mean) * rstd * g1.y + b1.y));
  }
}

__global__ __launch_bounds__(256) void final_matvec_kernel(
    const unsigned short* __restrict__ Hm, const float* __restrict__ wv,
    const float* __restrict__ b2, float* __restrict__ outp) {
  const long row = blockIdx.x;
  const int t = threadIdx.x;
  ushort4 hv = *(const ushort4*)&Hm[row * 1024 + t * 4];
  float4 wq = *(const float4*)&wv[t * 4];
  float s = bf2f(hv.x) * wq.x + bf2f(hv.y) * wq.y +
            bf2f(hv.z) * wq.z + bf2f(hv.w) * wq.w;
#pragma unroll
  for (int off = 32; off; off >>= 1) s += __shfl_xor(s, off, 64);
  __shared__ float red[4];
  if ((t & 63) == 0) red[t >> 6] = s;
  __syncthreads();
  if (t == 0) outp[row] = red[0] + red[1] + red[2] + red[3] + b2[0];
}

// ---------------------------------------------------------------------------
extern "C" void kernel_launch(void* const* d_in, const int* in_sizes, int n_in,
                              void* d_out, int out_size, void* d_ws,
                              size_t ws_size, hipStream_t stream) {
  const float* x_in = (const float*)d_in[0];
  const float* aln_g = (const float*)d_in[1];
  const float* aln_b = (const float*)d_in[2];
  const float* Wq_f = (const float*)d_in[3];
  const float* Wk_f = (const float*)d_in[4];
  const float* Wv_f = (const float*)d_in[5];
  const float* lnd_g = (const float*)d_in[6];
  const float* lnd_b = (const float*)d_in[7];
  const float* lnt_g = (const float*)d_in[8];
  const float* lnt_b = (const float*)d_in[9];
  const float* Wd1_f = (const float*)d_in[10];
  const float* bd1 = (const float*)d_in[11];
  const float* Wd2_f = (const float*)d_in[12];
  const float* bd2 = (const float*)d_in[13];
  const float* Wt1_f = (const float*)d_in[14];
  const float* bt1 = (const float*)d_in[15];
  const float* Wt2_f = (const float*)d_in[16];
  const float* bt2 = (const float*)d_in[17];
  const float* Wo1_f = (const float*)d_in[18];
  const float* bo1 = (const float*)d_in[19];
  const float* Wo2_f = (const float*)d_in[20];
  const float* bo2 = (const float*)d_in[21];

  const size_t R = 8192, D = 2048, HD = 1024;
  const size_t DD = D * D;
  const size_t WALL = (3 * 3 * DD + 4 * 2 * D * HD + HD * D) * 2;  // 108 MiB
  const size_t SLOT = 3 * DD * 2;                                  // 24 MiB
  const size_t ACT = R * D * 4 + R * D * 2 + R * 6144 * 2;         // 192 MiB

  auto cvt = [&](const float* src, unsigned short* dst, long n) {
    cvt_kernel<<<dim3((unsigned)(n / 1024)), dim3(256), 0, stream>>>(src, dst, n);
  };

  if (ws_size >= ACT + SLOT) {
    // ===================== fast path =====================
    const bool planAll = ws_size >= ACT + WALL;

    char* p = (char*)d_ws;
    unsigned short* Xb = (unsigned short*)p; p += R * D * 4;  // bf16 X (64MB slot)
    unsigned short* XN = (unsigned short*)p; p += R * D * 2;
    unsigned short* QKVb = (unsigned short*)p; p += R * 6144 * 2;
    unsigned short* Warea = (unsigned short*)p;

    unsigned short* H1d = QKVb;
    unsigned short* H1t = QKVb + R * 2048;
    unsigned short* Hfin = QKVb + R * 4096;
    unsigned short* DN = XN;
    unsigned short* TN = XN + R * HD;

    unsigned short* Wqkv_b = Warea;
    unsigned short* Wd1_b = Wqkv_b + 9 * DD;
    unsigned short* Wt1_b = Wd1_b + 2 * D * HD;
    unsigned short* Wd2_b = Wt1_b + 2 * D * HD;
    unsigned short* Wt2_b = Wd2_b + 2 * D * HD;
    unsigned short* Wo1_b = Wt2_b + 2 * D * HD;
    if (planAll) {
      CvtArgs ca;
      int s = 0;
      long pfx = 0;
      auto add = [&](const float* src, unsigned short* dst, long n) {
        ca.src[s] = src; ca.dst[s] = dst; ca.pfx[s] = pfx; pfx += n; ++s;
      };
      for (int n = 0; n < 3; ++n) {
        add(Wq_f + n * DD, Wqkv_b + n * 3 * DD + 0 * DD, (long)DD);
        add(Wk_f + n * DD, Wqkv_b + n * 3 * DD + 1 * DD, (long)DD);
        add(Wv_f + n * DD, Wqkv_b + n * 3 * DD + 2 * DD, (long)DD);
      }
      add(Wd1_f, Wd1_b, (long)(2 * D * HD));
      add(Wt1_f, Wt1_b, (long)(2 * D * HD));
      add(Wd2_f, Wd2_b, (long)(2 * D * HD));
      add(Wt2_f, Wt2_b, (long)(2 * D * HD));
      add(Wo1_f, Wo1_b, (long)(HD * D));
      ca.pfx[s] = pfx;
      ca.ns = s;
      cvt_multi_kernel<<<dim3((unsigned)(pfx / 1024)), dim3(256), 0, stream>>>(ca);
    }

    auto gemm = [&](const unsigned short* A, int lda, const unsigned short* B,
                    int N, int K, void* C, int ldc, const float* bias,
                    int relu, int of32, int resadd, const unsigned short* A2,
                    const unsigned short* B2, void* C2, const float* bias2) {
      const int dual = (A2 != nullptr);
      dim3 grid((dual ? 2 : 1) * (N / 128), 32);
      gemm2b_kernel<<<grid, dim3(512), 0, stream>>>(
          A, lda, B, K, C, ldc, bias, relu, of32, resadd, A2, B2, C2, bias2,
          dual);
    };

    for (int n = 0; n < 3; ++n) {
      // LN over residual stream: n=0 reads fp32 x_in, else bf16 Xb
      ln_kernel<2048><<<8192, 256, 0, stream>>>(
          (n == 0) ? (const void*)x_in : (const void*)Xb, n != 0, 2048,
          aln_g + n * D, aln_b + n * D, XN, 2048);
      const unsigned short* Wqkv;
      if (planAll) {
        Wqkv = Wqkv_b + (size_t)n * 3 * DD;
      } else {
        cvt(Wq_f + n * DD, Warea + 0 * DD, DD);
        cvt(Wk_f + n * DD, Warea + 1 * DD, DD);
        cvt(Wv_f + n * DD, Warea + 2 * DD, DD);
        Wqkv = Warea;
      }
      gemm(XN, 2048, Wqkv, 6144, 2048, QKVb, 6144, nullptr, 0, 0, 0,
           nullptr, nullptr, nullptr, nullptr);
      // X stream bf16: residual in (fp32 x_in at n=0, else Xb), out bf16 Xb
      attn_glue_kernel<<<8192, 512, 0, stream>>>(
          QKVb, QKVb + 2048, QKVb + 4096, 6144,
          (n == 0) ? (const void*)x_in : (const void*)Xb, n != 0,
          (void*)Xb, 1, nullptr,
          (n < 2) ? DN : nullptr, (n < 2) ? TN : nullptr,
          (n < 2) ? lnd_g + n * HD : nullptr, (n < 2) ? lnd_b + n * HD : nullptr,
          (n < 2) ? lnt_g + n * HD : nullptr, (n < 2) ? lnt_b + n * HD : nullptr);

      if (n < 2) {
        const size_t fo = (size_t)n * D * HD;
        const unsigned short *w1d, *w1t, *w2d, *w2t;
        if (planAll) {
          w1d = Wd1_b + fo; w1t = Wt1_b + fo; w2d = Wd2_b + fo; w2t = Wt2_b + fo;
        } else {
          cvt(Wd1_f + fo, Warea + 0 * D * HD, D * HD);
          cvt(Wt1_f + fo, Warea + 1 * D * HD, D * HD);
          cvt(Wd2_f + fo, Warea + 2 * D * HD, D * HD);
          cvt(Wt2_f + fo, Warea + 3 * D * HD, D * HD);
          w1d = Warea; w1t = Warea + D * HD; w2d = Warea + 2 * D * HD;
          w2t = Warea + 3 * D * HD;
        }
        // dual up-proj: DN -> H1d, TN -> H1t (bf16 out, relu)
        gemm(DN, 1024, w1d, 2048, 1024, H1d, 2048, bd1 + n * D, 1, 0, 0,
             TN, w1t, H1t, bt1 + n * D);
        // dual down-proj with bf16 resadd into Xb halves
        gemm(H1d, 2048, w2d, 1024, 2048, Xb, 2048, bd2 + n * HD, 0, 0, 1,
             H1t, w2t, Xb + HD, bt2 + n * HD);
      }
    }

    // final head: Hfin = relu(Xb @ Wo1^T + bo1); out = Hfin @ Wo2^T + bo2
    const unsigned short* Wo1p;
    if (planAll) {
      Wo1p = Wo1_b;
    } else {
      cvt(Wo1_f, Warea, HD * D);
      Wo1p = Warea;
    }
    gemm(Xb, 2048, Wo1p, 1024, 2048, Hfin, 1024, bo1, 1, 0, 0,
         nullptr, nullptr, nullptr, nullptr);
    final_matvec_kernel<<<8192, 256, 0, stream>>>(Hfin, Wo2_f, bo2,
                                                  (float*)d_out);
    return;
  }

  // ======================= legacy fallback path =======================
  const size_t PLB = R * D * 2;
  const size_t XFZ = R * D * 4;
  const size_t SLOT1 = DD * 2;
  const bool planAll = ws_size >= XFZ + 4 * PLB + WALL;
  const bool xIsF32 = planAll || ws_size >= XFZ + 4 * PLB + SLOT1;

  char* p = (char*)d_ws;
  float* Xf = nullptr;
  unsigned short* Xbb = nullptr;
  if (xIsF32) { Xf = (float*)p; p += XFZ; } else { Xbb = (unsigned short*)p; p += PLB; }
  unsigned short* XN = (unsigned short*)p; p += PLB;
  unsigned short* Qb = (unsigned short*)p; p += PLB;
  unsigned short* Kb = (unsigned short*)p; p += PLB;
  unsigned short* Vb = (unsigned short*)p; p += PLB;
  unsigned short* Warea = (unsigned short*)p;

  void* X = xIsF32 ? (void*)Xf : (void*)Xbb;
  const int xres_mode = xIsF32 ? 1 : 2;
  unsigned short* H1 = Qb;
  unsigned short* DN = XN;
  unsigned short* TN = XN + R * HD;
  unsigned short* Hfin = Vb;

  unsigned short* Wq_b = Warea;
  unsigned short* Wk_b = Wq_b + 3 * DD;
  unsigned short* Wv_b = Wk_b + 3 * DD;
  unsigned short* Wd1_b = Wv_b + 3 * DD;
  unsigned short* Wd2_b = Wd1_b + 2 * D * HD;
  unsigned short* Wt1_b = Wd2_b + 2 * D * HD;
  unsigned short* Wt2_b = Wt1_b + 2 * D * HD;
  unsigned short* Wo1_b = Wt2_b + 2 * D * HD;
  if (planAll) {
    cvt(Wq_f, Wq_b, 3 * DD);
    cvt(Wk_f, Wk_b, 3 * DD);
    cvt(Wv_f, Wv_b, 3 * DD);
    cvt(Wd1_f, Wd1_b, 2 * D * HD);
    cvt(Wd2_f, Wd2_b, 2 * D * HD);
    cvt(Wt1_f, Wt1_b, 2 * D * HD);
    cvt(Wt2_f, Wt2_b, 2 * D * HD);
    cvt(Wo1_f, Wo1_b, HD * D);
  }
  auto wbf = [&](const float* src_base, unsigned short* pre_base, size_t off,
                 size_t cnt) -> const unsigned short* {
    if (planAll) return pre_base + off;
    cvt(src_base + off, Warea, (long)cnt);
    return Warea;
  };
  auto gemm = [&](const unsigned short* A, int lda, const unsigned short* B,
                  int N, int K, void* C, int ldc, const float* bias,
                  const void* res, int res_mode, int ldres, int relu, int of32) {
    dim3 grid(N / 128, 8192 / 128);
    gemm_bt_kernel<<<grid, dim3(256), 0, stream>>>(
        A, lda, B, K, C, ldc, bias, res, res_mode, ldres, relu, of32);
  };

  for (int n = 0; n < 3; ++n) {
    const void* lin = (n == 0) ? (const void*)x_in : (const void*)X;
    const int lin_bf16 = (n == 0) ? 0 : (xIsF32 ? 0 : 1);
    ln_kernel<2048><<<8192, 256, 0, stream>>>(lin, lin_bf16, 2048,
                                              aln_g + n * D, aln_b + n * D, XN, 2048);
    const size_t wo = (size_t)n * DD;
    gemm(XN, 2048, wbf(Wq_f, Wq_b, wo, DD), 2048, 2048, Qb, 2048,
         nullptr, nullptr, 0, 0, 0, 0);
    gemm(XN, 2048, wbf(Wk_f, Wk_b, wo, DD), 2048, 2048, Kb, 2048,
         nullptr, nullptr, 0, 0, 0, 0);
    gemm(XN, 2048, wbf(Wv_f, Wv_b, wo, DD), 2048, 2048, Vb, 2048,
         nullptr, nullptr, 0, 0, 0, 0);
    attn_glue_kernel<<<8192, 512, 0, stream>>>(
        Qb, Kb, Vb, 2048, (n == 0) ? (const void*)x_in : (const void*)X,
        (n == 0) ? 0 : (xIsF32 ? 0 : 1), X, xIsF32 ? 0 : 1,
        (n == 2 && xIsF32) ? XN : nullptr,
        nullptr, nullptr, nullptr, nullptr, nullptr, nullptr);

    if (n < 2) {
      const size_t fo = (size_t)n * D * HD;
      ln_kernel<1024><<<8192, 256, 0, stream>>>(X, !xIsF32, 2048,
                                                lnd_g + n * HD, lnd_b + n * HD, DN, 1024);
      const void* Xt = xIsF32 ? (const void*)(Xf + HD) : (const void*)(Xbb + HD);
      ln_kernel<1024><<<8192, 256, 0, stream>>>(Xt, !xIsF32, 2048,
                                                lnt_g + n * HD, lnt_b + n * HD, TN, 1024);
      void* Xd2 = X;
      void* Xt2 = xIsF32 ? (void*)(Xf + HD) : (void*)(Xbb + HD);
      gemm(DN, 1024, wbf(Wd1_f, Wd1_b, fo, D * HD), 2048, 1024, H1, 2048,
           bd1 + n * D, nullptr, 0, 0, 1, 0);
      gemm(H1, 2048, wbf(Wd2_f, Wd2_b, fo, D * HD), 1024, 2048, Xd2, 2048,
           bd2 + n * HD, Xd2, xres_mode, 2048, 0, xIsF32 ? 1 : 0);
      gemm(TN, 1024, wbf(Wt1_f, Wt1_b, fo, D * HD), 2048, 1024, H1, 2048,
           bt1 + n * D, nullptr, 0, 0, 1, 0);
      gemm(H1, 2048, wbf(Wt2_f, Wt2_b, fo, D * HD), 1024, 2048, Xt2, 2048,
           bt2 + n * HD, Xt2, xres_mode, 2048, 0, xIsF32 ? 1 : 0);
    }
  }

  const unsigned short* Afin = xIsF32 ? XN : Xbb;
  gemm(Afin, 2048, wbf(Wo1_f, Wo1_b, 0, HD * D), 1024, 2048, Hfin, 1024,
       bo1, nullptr, 0, 0, 1, 0);
  final_matvec_kernel<<<8192, 256, 0, stream>>>(Hfin, Wo2_f, bo2, (float*)d_out);
}